// Round 6
// baseline (763.102 us; speedup 1.0000x reference)
//
#include <hip/hip_runtime.h>
#include <cmath>

#ifndef M_PI
#define M_PI 3.14159265358979323846
#endif

// Problem dims
#define NB      2
#define N_PIX   147456          // 384*384
#define L_LEN   147456
#define TENS_SZ ((long)NB * 64 * N_PIX)   // floats per 64-plane tensor

// small-region float offsets (at d_ws + 3*TENS_SZ floats)
#define OFF_C    0
#define OFF_CI   64
#define OFF_LAM  128
#define OFF_GRAM 256
#define OFF_QQ   2304
#define OFF_KK   2432
#define OFF_ATTN 2560

// stencil tile geometry
#define TW 128
#define TH 16
#define LW 136   // TW + 8 (4-col halo both sides, float4-aligned)
#define LH 18    // TH + 2
#define PLH 20   // TH + 4 (2-px halo for fused double stencil)
#define PVH 22   // TH + 6 (3-px halo for v_pre in pool2)

// ---------------------------------------------------------------- init consts
__global__ __launch_bounds__(64) void init_k(const float* __restrict__ lq1, const float* __restrict__ lk1,
                                             const float* __restrict__ lq2, const float* __restrict__ lk2,
                                             float* __restrict__ sm) {
  int t = threadIdx.x;
  int a = t >> 3, m = t & 7;
  double cv = 2.0 * cos(M_PI * (double)((2 * m + 1) * a) / 16.0);
  sm[OFF_C + a * 8 + m] = (float)cv;
  sm[OFF_CI + m * 8 + a] = (float)(cv / ((a == 0) ? 32.0 : 16.0));
  float p1 = lq1[t] * lk1[t];
  float p2 = lq2[t] * lk2[t];
  #pragma unroll
  for (int off = 32; off; off >>= 1) {
    p1 += __shfl_xor(p1, off, 64);
    p2 += __shfl_xor(p2, off, 64);
  }
  if (t == 0) sm[OFF_LAM] = expf(p1) - expf(p2) + 0.70082066706704813f;
  for (int i = t; i < 2304; i += 64) sm[OFF_GRAM + i] = 0.f;
}

__global__ void diag_k(float* out, float v) { out[0] = v; }

// ---------------------------------------------------------------- conv1x1: 64->64
__global__ __launch_bounds__(256) void conv1x1_k(const float* __restrict__ in, const float* __restrict__ w,
                                                 float* __restrict__ out) {
  __shared__ float ws[4096];   // w[co][ci], linear copy (16 KB)
  int t = threadIdx.x;
  for (int j = t; j < 1024; j += 256)
    *reinterpret_cast<float4*>(ws + j * 4) = *reinterpret_cast<const float4*>(w + j * 4);
  __syncthreads();

  long gp = (long)blockIdx.x * 256;
  int bb = (int)(gp / N_PIX);
  int p0 = (int)(gp - (long)bb * N_PIX);
  int lane = t & 63;
  int co0 = (t >> 6) * 16;

  const float* ip = in + (long)bb * 64 * N_PIX + p0 + lane * 4;
  const float* wp = ws + co0 * 64;

  float acc[16][4];   // [co][px]
  #pragma unroll
  for (int j = 0; j < 16; j++)
    #pragma unroll
    for (int p = 0; p < 4; p++) acc[j][p] = 0.f;

  for (int c4 = 0; c4 < 16; c4++) {
    float4 x0 = *reinterpret_cast<const float4*>(ip + (long)(c4 * 4 + 0) * N_PIX);
    float4 x1 = *reinterpret_cast<const float4*>(ip + (long)(c4 * 4 + 1) * N_PIX);
    float4 x2 = *reinterpret_cast<const float4*>(ip + (long)(c4 * 4 + 2) * N_PIX);
    float4 x3 = *reinterpret_cast<const float4*>(ip + (long)(c4 * 4 + 3) * N_PIX);
    #pragma unroll
    for (int j = 0; j < 16; j++) {
      float4 w4 = *reinterpret_cast<const float4*>(wp + j * 64 + c4 * 4);  // uniform -> broadcast
      acc[j][0] = fmaf(w4.x, x0.x, acc[j][0]);
      acc[j][0] = fmaf(w4.y, x1.x, acc[j][0]);
      acc[j][0] = fmaf(w4.z, x2.x, acc[j][0]);
      acc[j][0] = fmaf(w4.w, x3.x, acc[j][0]);
      acc[j][1] = fmaf(w4.x, x0.y, acc[j][1]);
      acc[j][1] = fmaf(w4.y, x1.y, acc[j][1]);
      acc[j][1] = fmaf(w4.z, x2.y, acc[j][1]);
      acc[j][1] = fmaf(w4.w, x3.y, acc[j][1]);
      acc[j][2] = fmaf(w4.x, x0.z, acc[j][2]);
      acc[j][2] = fmaf(w4.y, x1.z, acc[j][2]);
      acc[j][2] = fmaf(w4.z, x2.z, acc[j][2]);
      acc[j][2] = fmaf(w4.w, x3.z, acc[j][2]);
      acc[j][3] = fmaf(w4.x, x0.w, acc[j][3]);
      acc[j][3] = fmaf(w4.y, x1.w, acc[j][3]);
      acc[j][3] = fmaf(w4.z, x2.w, acc[j][3]);
      acc[j][3] = fmaf(w4.w, x3.w, acc[j][3]);
    }
  }

  float* op = out + (long)bb * 64 * N_PIX + p0 + lane * 4;
  #pragma unroll
  for (int j = 0; j < 16; j++)
    *reinterpret_cast<float4*>(op + (long)(co0 + j) * N_PIX) =
        make_float4(acc[j][0], acc[j][1], acc[j][2], acc[j][3]);
}

// ---------------------------------------------------------------- conv1x1 64->128: both nir halves, nir read once
__global__ __launch_bounds__(256) void conv1x1_nir2_k(const float* __restrict__ in, const float* __restrict__ w,
                                                      float* __restrict__ outk, float* __restrict__ outv) {
  __shared__ float ws[4096];
  int t = threadIdx.x;
  long gp = (long)blockIdx.x * 256;
  int bb = (int)(gp / N_PIX);
  int p0 = (int)(gp - (long)bb * N_PIX);
  int lane = t & 63;
  int co0 = (t >> 6) * 16;
  const float* ip = in + (long)bb * 64 * N_PIX + p0 + lane * 4;

  for (int half = 0; half < 2; half++) {
    __syncthreads();
    for (int j = t; j < 1024; j += 256)
      *reinterpret_cast<float4*>(ws + j * 4) = *reinterpret_cast<const float4*>(w + half * 4096 + j * 4);
    __syncthreads();
    const float* wp = ws + co0 * 64;
    float acc[16][4];
    #pragma unroll
    for (int j = 0; j < 16; j++)
      #pragma unroll
      for (int p = 0; p < 4; p++) acc[j][p] = 0.f;
    for (int c4 = 0; c4 < 16; c4++) {
      float4 x0 = *reinterpret_cast<const float4*>(ip + (long)(c4 * 4 + 0) * N_PIX);
      float4 x1 = *reinterpret_cast<const float4*>(ip + (long)(c4 * 4 + 1) * N_PIX);
      float4 x2 = *reinterpret_cast<const float4*>(ip + (long)(c4 * 4 + 2) * N_PIX);
      float4 x3 = *reinterpret_cast<const float4*>(ip + (long)(c4 * 4 + 3) * N_PIX);
      #pragma unroll
      for (int j = 0; j < 16; j++) {
        float4 w4 = *reinterpret_cast<const float4*>(wp + j * 64 + c4 * 4);
        acc[j][0] = fmaf(w4.x, x0.x, acc[j][0]);
        acc[j][0] = fmaf(w4.y, x1.x, acc[j][0]);
        acc[j][0] = fmaf(w4.z, x2.x, acc[j][0]);
        acc[j][0] = fmaf(w4.w, x3.x, acc[j][0]);
        acc[j][1] = fmaf(w4.x, x0.y, acc[j][1]);
        acc[j][1] = fmaf(w4.y, x1.y, acc[j][1]);
        acc[j][1] = fmaf(w4.z, x2.y, acc[j][1]);
        acc[j][1] = fmaf(w4.w, x3.y, acc[j][1]);
        acc[j][2] = fmaf(w4.x, x0.z, acc[j][2]);
        acc[j][2] = fmaf(w4.y, x1.z, acc[j][2]);
        acc[j][2] = fmaf(w4.z, x2.z, acc[j][2]);
        acc[j][2] = fmaf(w4.w, x3.z, acc[j][2]);
        acc[j][3] = fmaf(w4.x, x0.w, acc[j][3]);
        acc[j][3] = fmaf(w4.y, x1.w, acc[j][3]);
        acc[j][3] = fmaf(w4.z, x2.w, acc[j][3]);
        acc[j][3] = fmaf(w4.w, x3.w, acc[j][3]);
      }
    }
    float* op = (half ? outv : outk) + (long)bb * 64 * N_PIX + p0 + lane * 4;
    #pragma unroll
    for (int j = 0; j < 16; j++)
      *reinterpret_cast<float4*>(op + (long)(co0 + j) * N_PIX) =
          make_float4(acc[j][0], acc[j][1], acc[j][2], acc[j][3]);
  }
}

// ---------------------------------------------------------------- staging helper: guarded float4 tile load
__device__ __forceinline__ float4 load_g4(const float* __restrict__ p, int gy, int gx) {
  if ((unsigned)gy >= 384u) return make_float4(0.f, 0.f, 0.f, 0.f);
  if (gx >= 0 && gx + 3 < 384) return *reinterpret_cast<const float4*>(p + gy * 384 + gx);
  float e[4];
  #pragma unroll
  for (int i = 0; i < 4; i++) {
    int xx = gx + i;
    e[i] = ((unsigned)xx < 384u) ? p[gy * 384 + xx] : 0.f;
  }
  return make_float4(e[0], e[1], e[2], e[3]);
}

// ---------------------------------------------------------------- depthwise 3x3, LDS-tiled (fallback path)
__global__ __launch_bounds__(256) void dw3t_k(const float* __restrict__ in, const float* __restrict__ w,
                                              float* __restrict__ out) {
  __shared__ float sT[LH * LW];
  int plane = blockIdx.z;
  int ch = plane & 63;
  int x0 = blockIdx.x * TW, y0 = blockIdx.y * TH;
  const float* ip = in + (long)plane * N_PIX;
  int t = threadIdx.x;
  for (int j = t; j < LH * 34; j += 256) {
    int row = j / 34, c4 = j - row * 34;
    *reinterpret_cast<float4*>(sT + row * LW + c4 * 4) = load_g4(ip, y0 - 1 + row, x0 - 4 + c4 * 4);
  }
  __syncthreads();
  const float* wp = w + ch * 9;
  float w00 = wp[0], w01 = wp[1], w02 = wp[2];
  float w10 = wp[3], w11 = wp[4], w12 = wp[5];
  float w20 = wp[6], w21 = wp[7], w22 = wp[8];
  int col = t & 127, rg = t >> 7;
  int lc = col + 4;
  int r0 = rg * 8;
  float a0 = sT[r0 * LW + lc - 1],       a1 = sT[r0 * LW + lc],       a2 = sT[r0 * LW + lc + 1];
  float b0 = sT[(r0 + 1) * LW + lc - 1], b1 = sT[(r0 + 1) * LW + lc], b2 = sT[(r0 + 1) * LW + lc + 1];
  float* op = out + (long)plane * N_PIX + (long)(y0 + rg * 8) * 384 + x0 + col;
  #pragma unroll
  for (int i = 0; i < 8; i++) {
    int lr = r0 + i + 2;
    float c0 = sT[lr * LW + lc - 1], c1 = sT[lr * LW + lc], c2 = sT[lr * LW + lc + 1];
    float s = w00 * a0;
    s = fmaf(w01, a1, s); s = fmaf(w02, a2, s);
    s = fmaf(w10, b0, s); s = fmaf(w11, b1, s); s = fmaf(w12, b2, s);
    s = fmaf(w20, c0, s); s = fmaf(w21, c1, s); s = fmaf(w22, c2, s);
    op[i * 384] = s;
    a0 = b0; a1 = b1; a2 = b2;
    b0 = c0; b1 = c1; b2 = c2;
  }
}

// ---------------------------------------------------------------- fused dw3 + DCT
__global__ __launch_bounds__(256) void dw3dct_k(const float* __restrict__ in, const float* __restrict__ w,
                                                const float* __restrict__ sm,
                                                float* __restrict__ outf, float* __restrict__ outs) {
  __shared__ float sT[LH * LW];
  __shared__ float Cm[64];
  int t = threadIdx.x;
  if (t < 64) Cm[t] = sm[OFF_C + t];
  int plane = blockIdx.z;
  int ch = plane & 63;
  int x0 = blockIdx.x * TW, y0 = blockIdx.y * TH;
  const float* ip = in + (long)plane * N_PIX;
  for (int j = t; j < LH * 34; j += 256) {
    int row = j / 34, c4 = j - row * 34;
    *reinterpret_cast<float4*>(sT + row * LW + c4 * 4) = load_g4(ip, y0 - 1 + row, x0 - 4 + c4 * 4);
  }
  __syncthreads();
  const float* wp = w + ch * 9;
  float w00 = wp[0], w01 = wp[1], w02 = wp[2];
  float w10 = wp[3], w11 = wp[4], w12 = wp[5];
  float w20 = wp[6], w21 = wp[7], w22 = wp[8];
  int col = t & 127, rg = t >> 7;
  int lc = col + 4;
  int r0 = rg * 8;
  float r[8];
  {
    float a0 = sT[r0 * LW + lc - 1],       a1 = sT[r0 * LW + lc],       a2 = sT[r0 * LW + lc + 1];
    float b0 = sT[(r0 + 1) * LW + lc - 1], b1 = sT[(r0 + 1) * LW + lc], b2 = sT[(r0 + 1) * LW + lc + 1];
    #pragma unroll
    for (int i = 0; i < 8; i++) {
      int lr = r0 + i + 2;
      float c0 = sT[lr * LW + lc - 1], c1 = sT[lr * LW + lc], c2 = sT[lr * LW + lc + 1];
      float s = w00 * a0;
      s = fmaf(w01, a1, s); s = fmaf(w02, a2, s);
      s = fmaf(w10, b0, s); s = fmaf(w11, b1, s); s = fmaf(w12, b2, s);
      s = fmaf(w20, c0, s); s = fmaf(w21, c1, s); s = fmaf(w22, c2, s);
      r[i] = s;
      a0 = b0; a1 = b1; a2 = b2;
      b0 = c0; b1 = c1; b2 = c2;
    }
  }
  if (outs) {   // q chain: spatial output still needed downstream
    float* op = outs + (long)plane * N_PIX + (long)(y0 + r0) * 384 + x0 + col;
    #pragma unroll
    for (int i = 0; i < 8; i++) op[i * 384] = r[i];
  }
  __syncthreads();   // all sT stencil reads done
  #pragma unroll
  for (int i = 0; i < 8; i++) sT[(r0 + i + 1) * LW + lc] = r[i];
  __syncthreads();   // dw3 tile (rows 1..16, cols 4..131) visible
  // DCT: thread = (patch 0..31, row a 0..7); patch = prow*16 + pcol
  int patch = t >> 3, a = t & 7;
  int prow = patch >> 4, pcol = patch & 15;
  const float* xb = sT + (prow * 8 + 1) * LW + pcol * 8 + 4;
  float T[8];
  #pragma unroll
  for (int n = 0; n < 8; n++) {
    float s = 0.f;
    #pragma unroll
    for (int m = 0; m < 8; m++) s = fmaf(Cm[a * 8 + m], xb[m * LW + n], s);
    T[n] = s;
  }
  float o[8];
  #pragma unroll
  for (int b8 = 0; b8 < 8; b8++) {
    float s = 0.f;
    #pragma unroll
    for (int n = 0; n < 8; n++) s = fmaf(Cm[b8 * 8 + n], T[n], s);
    o[b8] = s;
  }
  int py = (y0 >> 3) + prow, px = (x0 >> 3) + pcol;
  float* op = outf + (long)plane * L_LEN + (long)(py * 48 + px) * 64 + a * 8;
  *reinterpret_cast<float4*>(op)     = make_float4(o[0], o[1], o[2], o[3]);
  *reinterpret_cast<float4*>(op + 4) = make_float4(o[4], o[5], o[6], o[7]);
}

// ---------------------------------------------------------------- stencil helper: 9 prelu'd outputs of one column
__device__ __forceinline__ void stencil_col9(const float* __restrict__ sb, int ci, int rs0,
                                             float w00, float w01, float w02,
                                             float w10, float w11, float w12,
                                             float w20, float w21, float w22,
                                             float alpha, bool xok, int y0,
                                             float* __restrict__ r) {
  float a0 = sb[rs0 * LW + ci - 1],       a1 = sb[rs0 * LW + ci],       a2 = sb[rs0 * LW + ci + 1];
  float b0 = sb[(rs0 + 1) * LW + ci - 1], b1 = sb[(rs0 + 1) * LW + ci], b2 = sb[(rs0 + 1) * LW + ci + 1];
  #pragma unroll
  for (int ii = 0; ii < 9; ii++) {
    int rs2 = rs0 + ii + 2;
    float c0 = sb[rs2 * LW + ci - 1], c1 = sb[rs2 * LW + ci], c2 = sb[rs2 * LW + ci + 1];
    float s = w00 * a0;
    s = fmaf(w01, a1, s); s = fmaf(w02, a2, s);
    s = fmaf(w10, b0, s); s = fmaf(w11, b1, s); s = fmaf(w12, b2, s);
    s = fmaf(w20, c0, s); s = fmaf(w21, c1, s); s = fmaf(w22, c2, s);
    s = (s >= 0.f) ? s : alpha * s;
    int gy = y0 - 1 + rs0 + ii;
    r[ii] = (xok && (unsigned)gy < 384u) ? s : 0.f;
    a0 = b0; a1 = b1; a2 = b2;
    b0 = c0; b1 = c1; b2 = c2;
  }
}

// ---------------------------------------------------------------- stencil helper: 10 raw dw3 outputs of one column
__device__ __forceinline__ void dw3_col10(const float* __restrict__ sb, int ci, int rs0,
                                          float w00, float w01, float w02,
                                          float w10, float w11, float w12,
                                          float w20, float w21, float w22,
                                          float* __restrict__ r) {
  float a0 = sb[rs0 * LW + ci - 1],       a1 = sb[rs0 * LW + ci],       a2 = sb[rs0 * LW + ci + 1];
  float b0 = sb[(rs0 + 1) * LW + ci - 1], b1 = sb[(rs0 + 1) * LW + ci], b2 = sb[(rs0 + 1) * LW + ci + 1];
  #pragma unroll
  for (int ii = 0; ii < 10; ii++) {
    int rs2 = rs0 + ii + 2;
    float c0 = sb[rs2 * LW + ci - 1], c1 = sb[rs2 * LW + ci], c2 = sb[rs2 * LW + ci + 1];
    float s = w00 * a0;
    s = fmaf(w01, a1, s); s = fmaf(w02, a2, s);
    s = fmaf(w10, b0, s); s = fmaf(w11, b1, s); s = fmaf(w12, b2, s);
    s = fmaf(w20, c0, s); s = fmaf(w21, c1, s); s = fmaf(w22, c2, s);
    r[ii] = s;
    a0 = b0; a1 = b1; a2 = b2;
    b0 = c0; b1 = c1; b2 = c2;
  }
}

// ---------------------------------------------------------------- pool (fallback): p1=q*om, p2=v-lam*v*om -> double stencil
__global__ __launch_bounds__(256) void pool_k(const float* __restrict__ q, const float* __restrict__ om,
                                              const float* __restrict__ v,
                                              const float* __restrict__ w1a, const float* __restrict__ a1p,
                                              const float* __restrict__ w1b,
                                              const float* __restrict__ w2a, const float* __restrict__ a2p,
                                              const float* __restrict__ w2b,
                                              const float* __restrict__ sm,
                                              float* __restrict__ outp) {
  __shared__ float s1[PLH * LW], s2[PLH * LW];
  int plane = blockIdx.z;
  int ch = plane & 63;
  int x0 = blockIdx.x * TW, y0 = blockIdx.y * TH;
  const float* qp = q  + (long)plane * N_PIX;
  const float* op = om + (long)plane * N_PIX;
  const float* vp = v  + (long)plane * N_PIX;
  float lam = sm[OFF_LAM];
  int t = threadIdx.x;
  for (int j = t; j < PLH * 34; j += 256) {
    int row = j / 34, c4 = j - row * 34;
    int gy = y0 - 2 + row, gx = x0 - 4 + c4 * 4;
    float4 qv = load_g4(qp, gy, gx);
    float4 ov = load_g4(op, gy, gx);
    float4 vv = load_g4(vp, gy, gx);
    *reinterpret_cast<float4*>(s1 + row * LW + c4 * 4) =
        make_float4(qv.x * ov.x, qv.y * ov.y, qv.z * ov.z, qv.w * ov.w);
    *reinterpret_cast<float4*>(s2 + row * LW + c4 * 4) =
        make_float4(vv.x - lam * vv.x * ov.x, vv.y - lam * vv.y * ov.y,
                    vv.z - lam * vv.z * ov.z, vv.w - lam * vv.w * ov.w);
  }
  __syncthreads();

  int ct = t & 127, rg = t >> 7;
  int rs0 = rg * 9;
  int ci0 = 3 + ct;
  int ci1 = 131 + ct;
  bool xok0 = (unsigned)(x0 - 4 + ci0) < 384u;
  bool xok1 = (unsigned)(x0 - 4 + ci1) < 384u;

  {
    const float* wp1 = w1a + ch * 9;
    float w00 = wp1[0], w01 = wp1[1], w02 = wp1[2], w10 = wp1[3], w11 = wp1[4],
          w12 = wp1[5], w20 = wp1[6], w21 = wp1[7], w22 = wp1[8];
    float alpha = a1p[0];
    float rm[9], re[9];
    stencil_col9(s1, ci0, rs0, w00, w01, w02, w10, w11, w12, w20, w21, w22, alpha, xok0, y0, rm);
    if (ct < 2)
      stencil_col9(s1, ci1, rs0, w00, w01, w02, w10, w11, w12, w20, w21, w22, alpha, xok1, y0, re);
    __syncthreads();
    #pragma unroll
    for (int ii = 0; ii < 9; ii++) s1[(rs0 + ii + 1) * LW + ci0] = rm[ii];
    if (ct < 2) {
      #pragma unroll
      for (int ii = 0; ii < 9; ii++) s1[(rs0 + ii + 1) * LW + ci1] = re[ii];
    }
  }
  {
    const float* wp2 = w2a + ch * 9;
    float w00 = wp2[0], w01 = wp2[1], w02 = wp2[2], w10 = wp2[3], w11 = wp2[4],
          w12 = wp2[5], w20 = wp2[6], w21 = wp2[7], w22 = wp2[8];
    float alpha = a2p[0];
    float rm[9], re[9];
    stencil_col9(s2, ci0, rs0, w00, w01, w02, w10, w11, w12, w20, w21, w22, alpha, xok0, y0, rm);
    if (ct < 2)
      stencil_col9(s2, ci1, rs0, w00, w01, w02, w10, w11, w12, w20, w21, w22, alpha, xok1, y0, re);
    __syncthreads();
    #pragma unroll
    for (int ii = 0; ii < 9; ii++) s2[(rs0 + ii + 1) * LW + ci0] = rm[ii];
    if (ct < 2) {
      #pragma unroll
      for (int ii = 0; ii < 9; ii++) s2[(rs0 + ii + 1) * LW + ci1] = re[ii];
    }
  }
  __syncthreads();
  {
    const float* wp1 = w1b + ch * 9;
    const float* wp2 = w2b + ch * 9;
    float p00 = wp1[0], p01 = wp1[1], p02 = wp1[2], p10 = wp1[3], p11 = wp1[4], p12 = wp1[5], p20 = wp1[6], p21 = wp1[7], p22 = wp1[8];
    float q00 = wp2[0], q01 = wp2[1], q02 = wp2[2], q10 = wp2[3], q11 = wp2[4], q12 = wp2[5], q20 = wp2[6], q21 = wp2[7], q22 = wp2[8];
    int col = t & 127, rg2 = t >> 7;
    int lc = col + 4;
    int rb = rg2 * 8 + 1;
    float xa0 = s1[rb * LW + lc - 1],       xa1 = s1[rb * LW + lc],       xa2 = s1[rb * LW + lc + 1];
    float xb0 = s1[(rb + 1) * LW + lc - 1], xb1 = s1[(rb + 1) * LW + lc], xb2 = s1[(rb + 1) * LW + lc + 1];
    float ya0 = s2[rb * LW + lc - 1],       ya1 = s2[rb * LW + lc],       ya2 = s2[rb * LW + lc + 1];
    float yb0 = s2[(rb + 1) * LW + lc - 1], yb1 = s2[(rb + 1) * LW + lc], yb2 = s2[(rb + 1) * LW + lc + 1];
    float* wo = outp + (long)plane * N_PIX + (long)(y0 + rg2 * 8) * 384 + x0 + col;
    #pragma unroll
    for (int i = 0; i < 8; i++) {
      int lr = rb + i + 2;
      float xc0 = s1[lr * LW + lc - 1], xc1 = s1[lr * LW + lc], xc2 = s1[lr * LW + lc + 1];
      float yc0 = s2[lr * LW + lc - 1], yc1 = s2[lr * LW + lc], yc2 = s2[lr * LW + lc + 1];
      float s = p00 * xa0;
      s = fmaf(p01, xa1, s); s = fmaf(p02, xa2, s);
      s = fmaf(p10, xb0, s); s = fmaf(p11, xb1, s); s = fmaf(p12, xb2, s);
      s = fmaf(p20, xc0, s); s = fmaf(p21, xc1, s); s = fmaf(p22, xc2, s);
      s = fmaf(q00, ya0, s); s = fmaf(q01, ya1, s); s = fmaf(q02, ya2, s);
      s = fmaf(q10, yb0, s); s = fmaf(q11, yb1, s); s = fmaf(q12, yb2, s);
      s = fmaf(q20, yc0, s); s = fmaf(q21, yc1, s); s = fmaf(q22, yc2, s);
      wo[i * 384] = s;
      xa0 = xb0; xa1 = xb1; xa2 = xb2; xb0 = xc0; xb1 = xc1; xb2 = xc2;
      ya0 = yb0; ya1 = yb1; ya2 = yb2; yb0 = yc0; yb1 = yc1; yb2 = yc2;
    }
  }
}

// ---------------------------------------------------------------- pool2: also fuses v = dw3(v_pre).
// s1[20]: p1 = q*om (rows gy=y0-2+r). s2[22]: v_pre (rows gy=y0-3+r) -> p2 at rows 1..20 -> u2 at rows 2..19.
// om re-read from global (L2-hot) at p2 build to avoid a third LDS buffer.
__global__ __launch_bounds__(256) void pool2_k(const float* __restrict__ q, const float* __restrict__ om,
                                               const float* __restrict__ vpre,
                                               const float* __restrict__ wv,
                                               const float* __restrict__ w1a, const float* __restrict__ a1p,
                                               const float* __restrict__ w1b,
                                               const float* __restrict__ w2a, const float* __restrict__ a2p,
                                               const float* __restrict__ w2b,
                                               const float* __restrict__ sm,
                                               float* __restrict__ outp) {
  __shared__ float s1[PLH * LW];
  __shared__ float s2[PVH * LW];
  int plane = blockIdx.z;
  int ch = plane & 63;
  int x0 = blockIdx.x * TW, y0 = blockIdx.y * TH;
  const float* qp = q + (long)plane * N_PIX;
  const float* omp_ = om + (long)plane * N_PIX;
  const float* vp = vpre + (long)plane * N_PIX;
  float lam = sm[OFF_LAM];
  int t = threadIdx.x;
  // phase A: stage v_pre (3px y-halo) and p1 = q*om (2px y-halo)
  for (int j = t; j < PVH * 34; j += 256) {
    int row = j / 34, c4 = j - row * 34;
    *reinterpret_cast<float4*>(s2 + row * LW + c4 * 4) = load_g4(vp, y0 - 3 + row, x0 - 4 + c4 * 4);
  }
  for (int j = t; j < PLH * 34; j += 256) {
    int row = j / 34, c4 = j - row * 34;
    int gy = y0 - 2 + row, gx = x0 - 4 + c4 * 4;
    float4 qv = load_g4(qp, gy, gx);
    float4 ov = load_g4(omp_, gy, gx);
    *reinterpret_cast<float4*>(s1 + row * LW + c4 * 4) =
        make_float4(qv.x * ov.x, qv.y * ov.y, qv.z * ov.z, qv.w * ov.w);
  }
  __syncthreads();

  int ct = t & 127, rg = t >> 7;
  // ---- phase V: v = dw3(v_pre); p2 = v - lam*v*om, masked ----
  float p2m[10], p2e[10];
  int rsV = rg * 10;            // reads s2 rows rsV..rsV+11; v rows rsV+1..rsV+10
  int ciV0 = 2 + ct;            // 2..129
  int ciV1 = 130 + ct;          // ct<4 -> 130..133
  {
    const float* wp = wv + ch * 9;
    float w00 = wp[0], w01 = wp[1], w02 = wp[2], w10 = wp[3], w11 = wp[4],
          w12 = wp[5], w20 = wp[6], w21 = wp[7], w22 = wp[8];
    dw3_col10(s2, ciV0, rsV, w00, w01, w02, w10, w11, w12, w20, w21, w22, p2m);
    if (ct < 4)
      dw3_col10(s2, ciV1, rsV, w00, w01, w02, w10, w11, w12, w20, w21, w22, p2e);
    int gx0 = x0 - 4 + ciV0, gx1 = x0 - 4 + ciV1;
    bool vx0 = (unsigned)gx0 < 384u, vx1 = (unsigned)gx1 < 384u;
    #pragma unroll
    for (int ii = 0; ii < 10; ii++) {
      int gy = y0 - 2 + rsV + ii;     // v row gy (s2 row rsV+1+ii)
      bool oky = (unsigned)gy < 384u;
      if (oky && vx0) {
        float o = omp_[gy * 384 + gx0];
        float vv = p2m[ii];
        p2m[ii] = vv - lam * vv * o;
      } else p2m[ii] = 0.f;
      if (ct < 4) {
        if (oky && vx1) {
          float o = omp_[gy * 384 + gx1];
          float vv = p2e[ii];
          p2e[ii] = vv - lam * vv * o;
        } else p2e[ii] = 0.f;
      }
    }
  }
  __syncthreads();   // all v_pre reads done
  // write p2 -> s2 rows 1..20 ; concurrently compute u1 from s1 (disjoint buffers)
  #pragma unroll
  for (int ii = 0; ii < 10; ii++) s2[(rsV + 1 + ii) * LW + ciV0] = p2m[ii];
  if (ct < 4) {
    #pragma unroll
    for (int ii = 0; ii < 10; ii++) s2[(rsV + 1 + ii) * LW + ciV1] = p2e[ii];
  }
  int rs0 = rg * 9;
  int ci0 = 3 + ct, ci1 = 131 + ct;
  bool xok0 = (unsigned)(x0 - 4 + ci0) < 384u;
  bool xok1 = (unsigned)(x0 - 4 + ci1) < 384u;
  float u1m[9], u1e[9];
  {
    const float* wp1 = w1a + ch * 9;
    float w00 = wp1[0], w01 = wp1[1], w02 = wp1[2], w10 = wp1[3], w11 = wp1[4],
          w12 = wp1[5], w20 = wp1[6], w21 = wp1[7], w22 = wp1[8];
    float alpha = a1p[0];
    stencil_col9(s1, ci0, rs0, w00, w01, w02, w10, w11, w12, w20, w21, w22, alpha, xok0, y0, u1m);
    if (ct < 2)
      stencil_col9(s1, ci1, rs0, w00, w01, w02, w10, w11, w12, w20, w21, w22, alpha, xok1, y0, u1e);
  }
  __syncthreads();   // p2 visible; all s1 (p1) reads done
  // write u1 -> s1 rows 1..18 ; concurrently compute u2 from p2 (s2 rows 1..20 via s2+LW)
  #pragma unroll
  for (int ii = 0; ii < 9; ii++) s1[(rs0 + ii + 1) * LW + ci0] = u1m[ii];
  if (ct < 2) {
    #pragma unroll
    for (int ii = 0; ii < 9; ii++) s1[(rs0 + ii + 1) * LW + ci1] = u1e[ii];
  }
  float u2m[9], u2e[9];
  {
    const float* wp2 = w2a + ch * 9;
    float w00 = wp2[0], w01 = wp2[1], w02 = wp2[2], w10 = wp2[3], w11 = wp2[4],
          w12 = wp2[5], w20 = wp2[6], w21 = wp2[7], w22 = wp2[8];
    float alpha = a2p[0];
    stencil_col9(s2 + LW, ci0, rs0, w00, w01, w02, w10, w11, w12, w20, w21, w22, alpha, xok0, y0, u2m);
    if (ct < 2)
      stencil_col9(s2 + LW, ci1, rs0, w00, w01, w02, w10, w11, w12, w20, w21, w22, alpha, xok1, y0, u2e);
  }
  __syncthreads();   // u1 visible; all p2 reads done
  // write u2 -> s2 rows 2..19 (via s2+LW at rows 1..18)
  {
    float* s2u = s2 + LW;
    #pragma unroll
    for (int ii = 0; ii < 9; ii++) s2u[(rs0 + ii + 1) * LW + ci0] = u2m[ii];
    if (ct < 2) {
      #pragma unroll
      for (int ii = 0; ii < 9; ii++) s2u[(rs0 + ii + 1) * LW + ci1] = u2e[ii];
    }
  }
  __syncthreads();   // u2 visible
  // ---- phase C: out = dw3(u1,w1b) + dw3(u2,w2b) ----
  {
    const float* s2u = s2 + LW;
    const float* wp1 = w1b + ch * 9;
    const float* wp2 = w2b + ch * 9;
    float p00 = wp1[0], p01 = wp1[1], p02 = wp1[2], p10 = wp1[3], p11 = wp1[4], p12 = wp1[5], p20 = wp1[6], p21 = wp1[7], p22 = wp1[8];
    float q00 = wp2[0], q01 = wp2[1], q02 = wp2[2], q10 = wp2[3], q11 = wp2[4], q12 = wp2[5], q20 = wp2[6], q21 = wp2[7], q22 = wp2[8];
    int col = t & 127, rg2 = t >> 7;
    int lc = col + 4;
    int rb = rg2 * 8 + 1;
    float xa0 = s1[rb * LW + lc - 1],        xa1 = s1[rb * LW + lc],        xa2 = s1[rb * LW + lc + 1];
    float xb0 = s1[(rb + 1) * LW + lc - 1],  xb1 = s1[(rb + 1) * LW + lc],  xb2 = s1[(rb + 1) * LW + lc + 1];
    float ya0 = s2u[rb * LW + lc - 1],       ya1 = s2u[rb * LW + lc],       ya2 = s2u[rb * LW + lc + 1];
    float yb0 = s2u[(rb + 1) * LW + lc - 1], yb1 = s2u[(rb + 1) * LW + lc], yb2 = s2u[(rb + 1) * LW + lc + 1];
    float* wo = outp + (long)plane * N_PIX + (long)(y0 + rg2 * 8) * 384 + x0 + col;
    #pragma unroll
    for (int i = 0; i < 8; i++) {
      int lr = rb + i + 2;
      float xc0 = s1[lr * LW + lc - 1],  xc1 = s1[lr * LW + lc],  xc2 = s1[lr * LW + lc + 1];
      float yc0 = s2u[lr * LW + lc - 1], yc1 = s2u[lr * LW + lc], yc2 = s2u[lr * LW + lc + 1];
      float s = p00 * xa0;
      s = fmaf(p01, xa1, s); s = fmaf(p02, xa2, s);
      s = fmaf(p10, xb0, s); s = fmaf(p11, xb1, s); s = fmaf(p12, xb2, s);
      s = fmaf(p20, xc0, s); s = fmaf(p21, xc1, s); s = fmaf(p22, xc2, s);
      s = fmaf(q00, ya0, s); s = fmaf(q01, ya1, s); s = fmaf(q02, ya2, s);
      s = fmaf(q10, yb0, s); s = fmaf(q11, yb1, s); s = fmaf(q12, yb2, s);
      s = fmaf(q20, yc0, s); s = fmaf(q21, yc1, s); s = fmaf(q22, yc2, s);
      wo[i * 384] = s;
      xa0 = xb0; xa1 = xb1; xa2 = xb2; xb0 = xc0; xb1 = xc1; xb2 = xc2;
      ya0 = yb0; ya1 = yb1; ya2 = yb2; yb0 = yc0; yb1 = yc1; yb2 = yc2;
    }
  }
}

// ---------------------------------------------------------------- DCT: spatial -> patch-flattened (fallback)
__global__ __launch_bounds__(256) void dct_k(const float* __restrict__ in,
                                             const float* __restrict__ sm, float* __restrict__ outf) {
  __shared__ float Cm[64];
  if (threadIdx.x < 64) Cm[threadIdx.x] = sm[OFF_C + threadIdx.x];
  __syncthreads();
  int pid = blockIdx.x * 256 + threadIdx.x;
  int wx = pid % 48;
  int t1 = pid / 48;
  int hy = t1 % 48; t1 /= 48;
  int ch = t1 & 63;
  int bb = t1 >> 6;
  const float* ip = in + (long)(bb * 64 + ch) * N_PIX + (hy * 8) * 384 + wx * 8;
  float X[8][8];
  #pragma unroll
  for (int r = 0; r < 8; r++) {
    float4 v0 = *reinterpret_cast<const float4*>(ip + r * 384);
    float4 v1 = *reinterpret_cast<const float4*>(ip + r * 384 + 4);
    X[r][0] = v0.x; X[r][1] = v0.y; X[r][2] = v0.z; X[r][3] = v0.w;
    X[r][4] = v1.x; X[r][5] = v1.y; X[r][6] = v1.z; X[r][7] = v1.w;
  }
  float T[8][8];
  #pragma unroll
  for (int a = 0; a < 8; a++)
    #pragma unroll
    for (int n = 0; n < 8; n++) {
      float s = 0.f;
      #pragma unroll
      for (int m = 0; m < 8; m++) s = fmaf(Cm[a * 8 + m], X[m][n], s);
      T[a][n] = s;
    }
  #pragma unroll
  for (int a = 0; a < 8; a++)
    #pragma unroll
    for (int b8 = 0; b8 < 8; b8++) {
      float s = 0.f;
      #pragma unroll
      for (int n = 0; n < 8; n++) s = fmaf(Cm[b8 * 8 + n], T[a][n], s);
      X[a][b8] = s;
    }
  float* op = outf + (long)(bb * 64 + ch) * L_LEN + (long)(hy * 48 + wx) * 64;
  float4* o4 = reinterpret_cast<float4*>(op);
  #pragma unroll
  for (int a = 0; a < 8; a++) {
    o4[a * 2]     = make_float4(X[a][0], X[a][1], X[a][2], X[a][3]);
    o4[a * 2 + 1] = make_float4(X[a][4], X[a][5], X[a][6], X[a][7]);
  }
}

// ---------------------------------------------------------------- Gram + norms, LDS-tiled
#define GS_P 132
__global__ __launch_bounds__(256) void gram_k(const float* __restrict__ qf, const float* __restrict__ kf,
                                              float* __restrict__ sm) {
  __shared__ float qs[16 * GS_P], ks[16 * GS_P];
  int t = threadIdx.x;
  int bh = blockIdx.y;
  int bb = bh >> 2, h = bh & 3;
  const float* qbase = qf + ((long)bb * 64 + h * 16) * L_LEN;
  const float* kbase = kf + ((long)bb * 64 + h * 16) * L_LEN;
  int c = t >> 4, d = t & 15;
  long l0 = (long)blockIdx.x * 2048;
  float g = 0.f, nq = 0.f, nk = 0.f;
  for (int chunk = 0; chunk < 16; chunk++) {
    long lc = l0 + chunk * 128;
    __syncthreads();
    for (int j = t; j < 512; j += 256) {
      int row = j >> 5, c4 = j & 31;
      *reinterpret_cast<float4*>(qs + row * GS_P + c4 * 4) =
          *reinterpret_cast<const float4*>(qbase + (long)row * L_LEN + lc + c4 * 4);
      *reinterpret_cast<float4*>(ks + row * GS_P + c4 * 4) =
          *reinterpret_cast<const float4*>(kbase + (long)row * L_LEN + lc + c4 * 4);
    }
    __syncthreads();
    #pragma unroll
    for (int i = 0; i < 128; i += 4) {
      float4 a = *reinterpret_cast<const float4*>(qs + c * GS_P + i);
      float4 b = *reinterpret_cast<const float4*>(ks + d * GS_P + i);
      g  = fmaf(a.x, b.x, g);  g  = fmaf(a.y, b.y, g);  g  = fmaf(a.z, b.z, g);  g  = fmaf(a.w, b.w, g);
      nq = fmaf(a.x, a.x, nq); nq = fmaf(a.y, a.y, nq); nq = fmaf(a.z, a.z, nq); nq = fmaf(a.w, a.w, nq);
      nk = fmaf(b.x, b.x, nk); nk = fmaf(b.y, b.y, nk); nk = fmaf(b.z, b.z, nk); nk = fmaf(b.w, b.w, nk);
    }
  }
  atomicAdd(&sm[OFF_GRAM + bh * 256 + c * 16 + d], g);
  if (d == 0) atomicAdd(&sm[OFF_QQ + bh * 16 + c], nq);
  if (c == 0) atomicAdd(&sm[OFF_KK + bh * 16 + d], nk);
}

// ---------------------------------------------------------------- normalize + temperature + softmax over d
__global__ __launch_bounds__(256) void attn_k(const float* __restrict__ temp, float* __restrict__ sm) {
  int bh = blockIdx.x;
  int h = bh & 3;
  int t = threadIdx.x;
  int c = t >> 4, d = t & 15;
  float qn = fmaxf(sqrtf(sm[OFF_QQ + bh * 16 + c]), 1e-12f);
  float kn = fmaxf(sqrtf(sm[OFF_KK + bh * 16 + d]), 1e-12f);
  float v = sm[OFF_GRAM + bh * 256 + t] / (qn * kn) * temp[h];
  float mx = v;
  #pragma unroll
  for (int o = 8; o; o >>= 1) mx = fmaxf(mx, __shfl_xor(mx, o, 16));
  float e = expf(v - mx);
  float s = e;
  #pragma unroll
  for (int o = 8; o; o >>= 1) s += __shfl_xor(s, o, 16);
  sm[OFF_ATTN + bh * 256 + t] = e / s;
}

// ---------------------------------------------------------------- fused combine + idct
#define CB_P 273
__global__ __launch_bounds__(256) void comb_idct_k(const float* __restrict__ qf, const float* __restrict__ kf,
                                                   const float* __restrict__ sm, float* __restrict__ out) {
  __shared__ float A[256];
  __shared__ float Ci[64];
  __shared__ float sb[16 * CB_P];
  int bh = blockIdx.y;
  int t = threadIdx.x;
  A[t] = sm[OFF_ATTN + bh * 256 + t];
  if (t < 64) Ci[t] = sm[OFF_CI + t];
  __syncthreads();
  int bb = bh >> 2, h = bh & 3;
  long l = (long)blockIdx.x * 256 + t;
  const float* qp = qf + ((long)bb * 64 + h * 16) * L_LEN + l;
  const float* kp = kf + ((long)bb * 64 + h * 16) * L_LEN + l;
  float p[16];
  #pragma unroll
  for (int d = 0; d < 16; d++) p[d] = qp[(long)d * L_LEN] * kp[(long)d * L_LEN];
  int pl_w = t >> 6, i_w = t & 63;
  #pragma unroll
  for (int c = 0; c < 16; c++) {
    float s = 0.f;
    #pragma unroll
    for (int d = 0; d < 16; d++) s = fmaf(A[c * 16 + d], p[d], s);
    sb[c * CB_P + pl_w * 68 + i_w] = s;
  }
  __syncthreads();
  int j = t & 3, c = (t >> 2) & 15, pl = t >> 6;
  const float* fb = sb + c * CB_P + pl * 68;
  float F[8][8];
  #pragma unroll
  for (int a = 0; a < 8; a++)
    #pragma unroll
    for (int b8 = 0; b8 < 8; b8++) F[a][b8] = fb[a * 8 + b8];
  int patch = blockIdx.x * 4 + pl;
  int hy = patch / 48, wx = patch - hy * 48;
  float* op = out + ((long)bb * 64 + h * 16 + c) * N_PIX + (long)(hy * 8) * 384 + wx * 8;
  #pragma unroll
  for (int mm = 0; mm < 2; mm++) {
    int m = 2 * j + mm;
    float T[8];
    #pragma unroll
    for (int b8 = 0; b8 < 8; b8++) {
      float s = 0.f;
      #pragma unroll
      for (int a = 0; a < 8; a++) s = fmaf(Ci[m * 8 + a], F[a][b8], s);
      T[b8] = s;
    }
    float o[8];
    #pragma unroll
    for (int n = 0; n < 8; n++) {
      float s = 0.f;
      #pragma unroll
      for (int b8 = 0; b8 < 8; b8++) s = fmaf(Ci[n * 8 + b8], T[b8], s);
      o[n] = s;
    }
    *reinterpret_cast<float4*>(op + m * 384)     = make_float4(o[0], o[1], o[2], o[3]);
    *reinterpret_cast<float4*>(op + m * 384 + 4) = make_float4(o[4], o[5], o[6], o[7]);
  }
}

// ---------------------------------------------------------------- o = attn @ (q_fft*k_fft), in place (fallback)
__global__ __launch_bounds__(256) void combine_k(float* __restrict__ qf, const float* __restrict__ kf,
                                                 const float* __restrict__ sm) {
  __shared__ float A[256];
  int bh = blockIdx.y;
  A[threadIdx.x] = sm[OFF_ATTN + bh * 256 + threadIdx.x];
  __syncthreads();
  int bb = bh >> 2, h = bh & 3;
  long l = (long)blockIdx.x * 256 + threadIdx.x;
  float* qp = qf + ((long)bb * 64 + h * 16) * L_LEN + l;
  const float* kp = kf + ((long)bb * 64 + h * 16) * L_LEN + l;
  float p[16];
  #pragma unroll
  for (int d = 0; d < 16; d++) p[d] = qp[(long)d * L_LEN] * kp[(long)d * L_LEN];
  #pragma unroll
  for (int c = 0; c < 16; c++) {
    float s = 0.f;
    #pragma unroll
    for (int d = 0; d < 16; d++) s = fmaf(A[c * 16 + d], p[d], s);
    qp[(long)c * L_LEN] = s;
  }
}

// ---------------------------------------------------------------- IDCT (fallback)
__global__ __launch_bounds__(256) void idct_k(const float* __restrict__ inf, const float* __restrict__ sm,
                                              float* __restrict__ out) {
  __shared__ float Ci[64];
  if (threadIdx.x < 64) Ci[threadIdx.x] = sm[OFF_CI + threadIdx.x];
  __syncthreads();
  int pid = blockIdx.x * 256 + threadIdx.x;
  int wx = pid % 48;
  int t1 = pid / 48;
  int hy = t1 % 48; t1 /= 48;
  int ch = t1 & 63;
  int bb = t1 >> 6;
  const float4* i4 = reinterpret_cast<const float4*>(inf + (long)(bb * 64 + ch) * L_LEN + (long)(hy * 48 + wx) * 64);
  float F[8][8];
  #pragma unroll
  for (int a = 0; a < 8; a++) {
    float4 v0 = i4[a * 2], v1 = i4[a * 2 + 1];
    F[a][0] = v0.x; F[a][1] = v0.y; F[a][2] = v0.z; F[a][3] = v0.w;
    F[a][4] = v1.x; F[a][5] = v1.y; F[a][6] = v1.z; F[a][7] = v1.w;
  }
  float T[8][8];
  #pragma unroll
  for (int m = 0; m < 8; m++)
    #pragma unroll
    for (int b8 = 0; b8 < 8; b8++) {
      float s = 0.f;
      #pragma unroll
      for (int a = 0; a < 8; a++) s = fmaf(Ci[m * 8 + a], F[a][b8], s);
      T[m][b8] = s;
    }
  #pragma unroll
  for (int m = 0; m < 8; m++)
    #pragma unroll
    for (int n = 0; n < 8; n++) {
      float s = 0.f;
      #pragma unroll
      for (int b8 = 0; b8 < 8; b8++) s = fmaf(Ci[n * 8 + b8], T[m][b8], s);
      F[m][n] = s;
    }
  float* op = out + (long)(bb * 64 + ch) * N_PIX + (hy * 8) * 384 + wx * 8;
  #pragma unroll
  for (int m = 0; m < 8; m++) {
    *reinterpret_cast<float4*>(op + m * 384)     = make_float4(F[m][0], F[m][1], F[m][2], F[m][3]);
    *reinterpret_cast<float4*>(op + m * 384 + 4) = make_float4(F[m][4], F[m][5], F[m][6], F[m][7]);
  }
}

// ---------------------------------------------------------------- launch
extern "C" void kernel_launch(void* const* d_in, const int* in_sizes, int n_in,
                              void* d_out, int out_size, void* d_ws, size_t ws_size,
                              hipStream_t stream) {
  const float* x            = (const float*)d_in[0];
  const float* nir          = (const float*)d_in[1];
  const float* w_hidden     = (const float*)d_in[2];
  const float* w_hidden_nir = (const float*)d_in[3];
  const float* w_dw         = (const float*)d_in[4];
  const float* w_dw_nir     = (const float*)d_in[5];
  const float* temperature  = (const float*)d_in[6];
  const float* w_proj_mid   = (const float*)d_in[7];
  const float* w_proj_out   = (const float*)d_in[8];
  const float* w_p1a        = (const float*)d_in[9];
  const float* a_p1         = (const float*)d_in[10];
  const float* w_p1b        = (const float*)d_in[11];
  const float* w_p2a        = (const float*)d_in[12];
  const float* a_p2         = (const float*)d_in[13];
  const float* w_p2b        = (const float*)d_in[14];
  const float* lq1          = (const float*)d_in[15];
  const float* lk1          = (const float*)d_in[16];
  const float* lq2          = (const float*)d_in[17];
  const float* lk2          = (const float*)d_in[18];

  float* OUT = (float*)d_out;
  float* W0 = (float*)d_ws;
  float* W1 = W0 + TENS_SZ;
  float* W2 = W1 + TENS_SZ;
  float* SM = W2 + TENS_SZ;
  float* W3 = SM + 8192;           // 4th tensor (only used if workspace allows)

  size_t needed3 = (size_t)3 * TENS_SZ * sizeof(float) + 32768;
  size_t needed4 = ((size_t)4 * TENS_SZ + 8192) * sizeof(float);
  if (ws_size < needed3) {
    diag_k<<<1, 1, 0, stream>>>(OUT, 1000.0f + (float)(ws_size >> 20));
    return;
  }
  bool big = ws_size >= needed4;

  dim3 blk256(256);
  dim3 gridST(3, 24, NB * 64);     // stencil tiles: 128x16 over 384x384, 128 planes

  init_k<<<1, 64, 0, stream>>>(lq1, lk1, lq2, lk2, SM);

  if (big) {
    // k_pre -> W0, v_pre -> W1 (nir read once; v_pre persists until pool2)
    conv1x1_nir2_k<<<1152, blk256, 0, stream>>>(nir, w_hidden_nir, W0, W1);
    // k_fft = dct(dw3(k_pre)) -> W2
    dw3dct_k<<<gridST, blk256, 0, stream>>>(W0, w_dw_nir, SM, W2, nullptr);
    // hidden = conv1x1(x, w_hidden) -> W0
    conv1x1_k<<<1152, blk256, 0, stream>>>(x, w_hidden, W0);
    // q spatial -> OUT, q_fft -> W3
    dw3dct_k<<<gridST, blk256, 0, stream>>>(W0, w_dw, SM, W3, OUT);
    // Gram + norms + softmax
    gram_k<<<dim3(72, 8), blk256, 0, stream>>>(W3, W2, SM);
    attn_k<<<8, blk256, 0, stream>>>(temperature, SM);
    // o spatial -> W0 (fused combine+idct)
    comb_idct_k<<<dim3(576, 8), blk256, 0, stream>>>(W3, W2, SM, W0);
    // om = conv1x1(o, w_proj_mid) -> W2
    conv1x1_k<<<1152, blk256, 0, stream>>>(W0, w_proj_mid, W2);
    // pool2 (includes v = dw3(v_pre)): q=OUT, om=W2, v_pre=W1 -> outp in W3
    pool2_k<<<gridST, blk256, 0, stream>>>(OUT, W2, W1, w_dw_nir + 64 * 9,
                                           w_p1a, a_p1, w_p1b, w_p2a, a_p2, w_p2b, SM, W3);
    // final = conv1x1(outp, w_proj_out) -> OUT
    conv1x1_k<<<1152, blk256, 0, stream>>>(W3, w_proj_out, OUT);
  } else {
    conv1x1_k<<<1152, blk256, 0, stream>>>(x, w_hidden, W0);
    dw3t_k<<<gridST, blk256, 0, stream>>>(W0, w_dw, OUT);
    conv1x1_k<<<1152, blk256, 0, stream>>>(nir, w_hidden_nir, W0);
    dw3t_k<<<gridST, blk256, 0, stream>>>(W0, w_dw_nir, W1);
    conv1x1_k<<<1152, blk256, 0, stream>>>(nir, w_hidden_nir + 64 * 64, W0);
    dw3t_k<<<gridST, blk256, 0, stream>>>(W0, w_dw_nir + 64 * 9, W2);
    dct_k<<<1152, blk256, 0, stream>>>(W1, SM, W0);
    dct_k<<<1152, blk256, 0, stream>>>(OUT, SM, W1);
    gram_k<<<dim3(72, 8), blk256, 0, stream>>>(W1, W0, SM);
    attn_k<<<8, blk256, 0, stream>>>(temperature, SM);
    combine_k<<<dim3(576, 8), blk256, 0, stream>>>(W1, W0, SM);
    idct_k<<<1152, blk256, 0, stream>>>(W1, SM, W0);
    conv1x1_k<<<1152, blk256, 0, stream>>>(W0, w_proj_mid, W1);
    pool_k<<<gridST, blk256, 0, stream>>>(OUT, W1, W2, w_p1a, a_p1, w_p1b, w_p2a, a_p2, w_p2b, SM, W0);
    conv1x1_k<<<1152, blk256, 0, stream>>>(W0, w_proj_out, OUT);
  }
}

// Round 7
// 712.020 us; speedup vs baseline: 1.0717x; 1.0717x over previous
//
#include <hip/hip_runtime.h>
#include <cmath>

#ifndef M_PI
#define M_PI 3.14159265358979323846
#endif

// Problem dims
#define NB      2
#define N_PIX   147456          // 384*384
#define L_LEN   147456
#define TENS_SZ ((long)NB * 64 * N_PIX)   // floats per 64-plane tensor

// small-region float offsets (at d_ws + 3*TENS_SZ floats)
#define OFF_C    0
#define OFF_CI   64
#define OFF_LAM  128
#define OFF_GRAM 256
#define OFF_QQ   2304
#define OFF_KK   2432
#define OFF_ATTN 2560

// stencil tile geometry
#define TW 128
#define TH 16
#define LW 136   // TW + 8 (4-col halo both sides, float4-aligned)
#define LH 18    // TH + 2
#define PVH 22   // TH + 6 (3-px halo for hidden/v_pre in pool3)

// ---------------------------------------------------------------- init consts
__global__ __launch_bounds__(64) void init_k(const float* __restrict__ lq1, const float* __restrict__ lk1,
                                             const float* __restrict__ lq2, const float* __restrict__ lk2,
                                             float* __restrict__ sm) {
  int t = threadIdx.x;
  int a = t >> 3, m = t & 7;
  double cv = 2.0 * cos(M_PI * (double)((2 * m + 1) * a) / 16.0);
  sm[OFF_C + a * 8 + m] = (float)cv;
  sm[OFF_CI + m * 8 + a] = (float)(cv / ((a == 0) ? 32.0 : 16.0));
  float p1 = lq1[t] * lk1[t];
  float p2 = lq2[t] * lk2[t];
  #pragma unroll
  for (int off = 32; off; off >>= 1) {
    p1 += __shfl_xor(p1, off, 64);
    p2 += __shfl_xor(p2, off, 64);
  }
  if (t == 0) sm[OFF_LAM] = expf(p1) - expf(p2) + 0.70082066706704813f;
  for (int i = t; i < 2304; i += 64) sm[OFF_GRAM + i] = 0.f;
}

__global__ void diag_k(float* out, float v) { out[0] = v; }

// ---------------------------------------------------------------- conv1x1: 64->64
__global__ __launch_bounds__(256) void conv1x1_k(const float* __restrict__ in, const float* __restrict__ w,
                                                 float* __restrict__ out) {
  __shared__ float ws[4096];   // w[co][ci], linear copy (16 KB)
  int t = threadIdx.x;
  for (int j = t; j < 1024; j += 256)
    *reinterpret_cast<float4*>(ws + j * 4) = *reinterpret_cast<const float4*>(w + j * 4);
  __syncthreads();

  long gp = (long)blockIdx.x * 256;
  int bb = (int)(gp / N_PIX);
  int p0 = (int)(gp - (long)bb * N_PIX);
  int lane = t & 63;
  int co0 = (t >> 6) * 16;

  const float* ip = in + (long)bb * 64 * N_PIX + p0 + lane * 4;
  const float* wp = ws + co0 * 64;

  float acc[16][4];   // [co][px]
  #pragma unroll
  for (int j = 0; j < 16; j++)
    #pragma unroll
    for (int p = 0; p < 4; p++) acc[j][p] = 0.f;

  for (int c4 = 0; c4 < 16; c4++) {
    float4 x0 = *reinterpret_cast<const float4*>(ip + (long)(c4 * 4 + 0) * N_PIX);
    float4 x1 = *reinterpret_cast<const float4*>(ip + (long)(c4 * 4 + 1) * N_PIX);
    float4 x2 = *reinterpret_cast<const float4*>(ip + (long)(c4 * 4 + 2) * N_PIX);
    float4 x3 = *reinterpret_cast<const float4*>(ip + (long)(c4 * 4 + 3) * N_PIX);
    #pragma unroll
    for (int j = 0; j < 16; j++) {
      float4 w4 = *reinterpret_cast<const float4*>(wp + j * 64 + c4 * 4);  // uniform -> broadcast
      acc[j][0] = fmaf(w4.x, x0.x, acc[j][0]);
      acc[j][0] = fmaf(w4.y, x1.x, acc[j][0]);
      acc[j][0] = fmaf(w4.z, x2.x, acc[j][0]);
      acc[j][0] = fmaf(w4.w, x3.x, acc[j][0]);
      acc[j][1] = fmaf(w4.x, x0.y, acc[j][1]);
      acc[j][1] = fmaf(w4.y, x1.y, acc[j][1]);
      acc[j][1] = fmaf(w4.z, x2.y, acc[j][1]);
      acc[j][1] = fmaf(w4.w, x3.y, acc[j][1]);
      acc[j][2] = fmaf(w4.x, x0.z, acc[j][2]);
      acc[j][2] = fmaf(w4.y, x1.z, acc[j][2]);
      acc[j][2] = fmaf(w4.z, x2.z, acc[j][2]);
      acc[j][2] = fmaf(w4.w, x3.z, acc[j][2]);
      acc[j][3] = fmaf(w4.x, x0.w, acc[j][3]);
      acc[j][3] = fmaf(w4.y, x1.w, acc[j][3]);
      acc[j][3] = fmaf(w4.z, x2.w, acc[j][3]);
      acc[j][3] = fmaf(w4.w, x3.w, acc[j][3]);
    }
  }

  float* op = out + (long)bb * 64 * N_PIX + p0 + lane * 4;
  #pragma unroll
  for (int j = 0; j < 16; j++)
    *reinterpret_cast<float4*>(op + (long)(co0 + j) * N_PIX) =
        make_float4(acc[j][0], acc[j][1], acc[j][2], acc[j][3]);
}

// ---------------------------------------------------------------- conv1x1 64->128: both nir halves, nir read once
__global__ __launch_bounds__(256) void conv1x1_nir2_k(const float* __restrict__ in, const float* __restrict__ w,
                                                      float* __restrict__ outk, float* __restrict__ outv) {
  __shared__ float ws[4096];
  int t = threadIdx.x;
  long gp = (long)blockIdx.x * 256;
  int bb = (int)(gp / N_PIX);
  int p0 = (int)(gp - (long)bb * N_PIX);
  int lane = t & 63;
  int co0 = (t >> 6) * 16;
  const float* ip = in + (long)bb * 64 * N_PIX + p0 + lane * 4;

  for (int half = 0; half < 2; half++) {
    __syncthreads();
    for (int j = t; j < 1024; j += 256)
      *reinterpret_cast<float4*>(ws + j * 4) = *reinterpret_cast<const float4*>(w + half * 4096 + j * 4);
    __syncthreads();
    const float* wp = ws + co0 * 64;
    float acc[16][4];
    #pragma unroll
    for (int j = 0; j < 16; j++)
      #pragma unroll
      for (int p = 0; p < 4; p++) acc[j][p] = 0.f;
    for (int c4 = 0; c4 < 16; c4++) {
      float4 x0 = *reinterpret_cast<const float4*>(ip + (long)(c4 * 4 + 0) * N_PIX);
      float4 x1 = *reinterpret_cast<const float4*>(ip + (long)(c4 * 4 + 1) * N_PIX);
      float4 x2 = *reinterpret_cast<const float4*>(ip + (long)(c4 * 4 + 2) * N_PIX);
      float4 x3 = *reinterpret_cast<const float4*>(ip + (long)(c4 * 4 + 3) * N_PIX);
      #pragma unroll
      for (int j = 0; j < 16; j++) {
        float4 w4 = *reinterpret_cast<const float4*>(wp + j * 64 + c4 * 4);
        acc[j][0] = fmaf(w4.x, x0.x, acc[j][0]);
        acc[j][0] = fmaf(w4.y, x1.x, acc[j][0]);
        acc[j][0] = fmaf(w4.z, x2.x, acc[j][0]);
        acc[j][0] = fmaf(w4.w, x3.x, acc[j][0]);
        acc[j][1] = fmaf(w4.x, x0.y, acc[j][1]);
        acc[j][1] = fmaf(w4.y, x1.y, acc[j][1]);
        acc[j][1] = fmaf(w4.z, x2.y, acc[j][1]);
        acc[j][1] = fmaf(w4.w, x3.y, acc[j][1]);
        acc[j][2] = fmaf(w4.x, x0.z, acc[j][2]);
        acc[j][2] = fmaf(w4.y, x1.z, acc[j][2]);
        acc[j][2] = fmaf(w4.z, x2.z, acc[j][2]);
        acc[j][2] = fmaf(w4.w, x3.z, acc[j][2]);
        acc[j][3] = fmaf(w4.x, x0.w, acc[j][3]);
        acc[j][3] = fmaf(w4.y, x1.w, acc[j][3]);
        acc[j][3] = fmaf(w4.z, x2.w, acc[j][3]);
        acc[j][3] = fmaf(w4.w, x3.w, acc[j][3]);
      }
    }
    float* op = (half ? outv : outk) + (long)bb * 64 * N_PIX + p0 + lane * 4;
    #pragma unroll
    for (int j = 0; j < 16; j++)
      *reinterpret_cast<float4*>(op + (long)(co0 + j) * N_PIX) =
          make_float4(acc[j][0], acc[j][1], acc[j][2], acc[j][3]);
  }
}

// ---------------------------------------------------------------- staging helper: guarded float4 tile load
__device__ __forceinline__ float4 load_g4(const float* __restrict__ p, int gy, int gx) {
  if ((unsigned)gy >= 384u) return make_float4(0.f, 0.f, 0.f, 0.f);
  if (gx >= 0 && gx + 3 < 384) return *reinterpret_cast<const float4*>(p + gy * 384 + gx);
  float e[4];
  #pragma unroll
  for (int i = 0; i < 4; i++) {
    int xx = gx + i;
    e[i] = ((unsigned)xx < 384u) ? p[gy * 384 + xx] : 0.f;
  }
  return make_float4(e[0], e[1], e[2], e[3]);
}

// ---------------------------------------------------------------- fused dw3 + DCT (tile 16x128 = 2x16 patches)
__global__ __launch_bounds__(256) void dw3dct_k(const float* __restrict__ in, const float* __restrict__ w,
                                                const float* __restrict__ sm,
                                                float* __restrict__ outf) {
  __shared__ float sT[LH * LW];
  __shared__ float Cm[64];
  int t = threadIdx.x;
  if (t < 64) Cm[t] = sm[OFF_C + t];
  int plane = blockIdx.z;
  int ch = plane & 63;
  int x0 = blockIdx.x * TW, y0 = blockIdx.y * TH;
  const float* ip = in + (long)plane * N_PIX;
  for (int j = t; j < LH * 34; j += 256) {
    int row = j / 34, c4 = j - row * 34;
    *reinterpret_cast<float4*>(sT + row * LW + c4 * 4) = load_g4(ip, y0 - 1 + row, x0 - 4 + c4 * 4);
  }
  __syncthreads();
  const float* wp = w + ch * 9;
  float w00 = wp[0], w01 = wp[1], w02 = wp[2];
  float w10 = wp[3], w11 = wp[4], w12 = wp[5];
  float w20 = wp[6], w21 = wp[7], w22 = wp[8];
  int col = t & 127, rg = t >> 7;
  int lc = col + 4;
  int r0 = rg * 8;
  float r[8];
  {
    float a0 = sT[r0 * LW + lc - 1],       a1 = sT[r0 * LW + lc],       a2 = sT[r0 * LW + lc + 1];
    float b0 = sT[(r0 + 1) * LW + lc - 1], b1 = sT[(r0 + 1) * LW + lc], b2 = sT[(r0 + 1) * LW + lc + 1];
    #pragma unroll
    for (int i = 0; i < 8; i++) {
      int lr = r0 + i + 2;
      float c0 = sT[lr * LW + lc - 1], c1 = sT[lr * LW + lc], c2 = sT[lr * LW + lc + 1];
      float s = w00 * a0;
      s = fmaf(w01, a1, s); s = fmaf(w02, a2, s);
      s = fmaf(w10, b0, s); s = fmaf(w11, b1, s); s = fmaf(w12, b2, s);
      s = fmaf(w20, c0, s); s = fmaf(w21, c1, s); s = fmaf(w22, c2, s);
      r[i] = s;
      a0 = b0; a1 = b1; a2 = b2;
      b0 = c0; b1 = c1; b2 = c2;
    }
  }
  __syncthreads();   // all sT stencil reads done
  #pragma unroll
  for (int i = 0; i < 8; i++) sT[(r0 + i + 1) * LW + lc] = r[i];
  __syncthreads();   // dw3 tile (rows 1..16, cols 4..131) visible
  // DCT: thread = (patch 0..31, row a 0..7); patch = prow*16 + pcol
  int patch = t >> 3, a = t & 7;
  int prow = patch >> 4, pcol = patch & 15;
  const float* xb = sT + (prow * 8 + 1) * LW + pcol * 8 + 4;
  float T[8];
  #pragma unroll
  for (int n = 0; n < 8; n++) {
    float s = 0.f;
    #pragma unroll
    for (int m = 0; m < 8; m++) s = fmaf(Cm[a * 8 + m], xb[m * LW + n], s);
    T[n] = s;
  }
  float o[8];
  #pragma unroll
  for (int b8 = 0; b8 < 8; b8++) {
    float s = 0.f;
    #pragma unroll
    for (int n = 0; n < 8; n++) s = fmaf(Cm[b8 * 8 + n], T[n], s);
    o[b8] = s;
  }
  int py = (y0 >> 3) + prow, px = (x0 >> 3) + pcol;
  float* op = outf + (long)plane * L_LEN + (long)(py * 48 + px) * 64 + a * 8;
  *reinterpret_cast<float4*>(op)     = make_float4(o[0], o[1], o[2], o[3]);
  *reinterpret_cast<float4*>(op + 4) = make_float4(o[4], o[5], o[6], o[7]);
}

// ---------------------------------------------------------------- stencil helper: 9 prelu'd outputs of one column
__device__ __forceinline__ void stencil_col9(const float* __restrict__ sb, int ci, int rs0,
                                             float w00, float w01, float w02,
                                             float w10, float w11, float w12,
                                             float w20, float w21, float w22,
                                             float alpha, bool xok, int y0,
                                             float* __restrict__ r) {
  float a0 = sb[rs0 * LW + ci - 1],       a1 = sb[rs0 * LW + ci],       a2 = sb[rs0 * LW + ci + 1];
  float b0 = sb[(rs0 + 1) * LW + ci - 1], b1 = sb[(rs0 + 1) * LW + ci], b2 = sb[(rs0 + 1) * LW + ci + 1];
  #pragma unroll
  for (int ii = 0; ii < 9; ii++) {
    int rs2 = rs0 + ii + 2;
    float c0 = sb[rs2 * LW + ci - 1], c1 = sb[rs2 * LW + ci], c2 = sb[rs2 * LW + ci + 1];
    float s = w00 * a0;
    s = fmaf(w01, a1, s); s = fmaf(w02, a2, s);
    s = fmaf(w10, b0, s); s = fmaf(w11, b1, s); s = fmaf(w12, b2, s);
    s = fmaf(w20, c0, s); s = fmaf(w21, c1, s); s = fmaf(w22, c2, s);
    s = (s >= 0.f) ? s : alpha * s;
    int gy = y0 - 1 + rs0 + ii;
    r[ii] = (xok && (unsigned)gy < 384u) ? s : 0.f;
    a0 = b0; a1 = b1; a2 = b2;
    b0 = c0; b1 = c1; b2 = c2;
  }
}

// ---------------------------------------------------------------- stencil helper: 10 raw dw3 outputs of one column
__device__ __forceinline__ void dw3_col10(const float* __restrict__ sb, int ci, int rs0,
                                          float w00, float w01, float w02,
                                          float w10, float w11, float w12,
                                          float w20, float w21, float w22,
                                          float* __restrict__ r) {
  float a0 = sb[rs0 * LW + ci - 1],       a1 = sb[rs0 * LW + ci],       a2 = sb[rs0 * LW + ci + 1];
  float b0 = sb[(rs0 + 1) * LW + ci - 1], b1 = sb[(rs0 + 1) * LW + ci], b2 = sb[(rs0 + 1) * LW + ci + 1];
  #pragma unroll
  for (int ii = 0; ii < 10; ii++) {
    int rs2 = rs0 + ii + 2;
    float c0 = sb[rs2 * LW + ci - 1], c1 = sb[rs2 * LW + ci], c2 = sb[rs2 * LW + ci + 1];
    float s = w00 * a0;
    s = fmaf(w01, a1, s); s = fmaf(w02, a2, s);
    s = fmaf(w10, b0, s); s = fmaf(w11, b1, s); s = fmaf(w12, b2, s);
    s = fmaf(w20, c0, s); s = fmaf(w21, c1, s); s = fmaf(w22, c2, s);
    r[ii] = s;
    a0 = b0; a1 = b1; a2 = b2;
    b0 = c0; b1 = c1; b2 = c2;
  }
}

// ---------------------------------------------------------------- pool3: q = dw3(hidden), v = dw3(v_pre) in LDS;
// p1 = q*om, p2 = v - lam*v*om (om from global, one load serves both);
// u = prelu(dw3(p, wa), a) register-staged; out = dw3(u1,w1b)+dw3(u2,w2b).
// s1/s2: 22 rows each (3-px halo). p stored rows 1..20; u rows 2..19.
__global__ __launch_bounds__(256) void pool3_k(const float* __restrict__ hidden, const float* __restrict__ vpre,
                                               const float* __restrict__ om,
                                               const float* __restrict__ wq, const float* __restrict__ wv,
                                               const float* __restrict__ w1a, const float* __restrict__ a1p,
                                               const float* __restrict__ w1b,
                                               const float* __restrict__ w2a, const float* __restrict__ a2p,
                                               const float* __restrict__ w2b,
                                               const float* __restrict__ sm,
                                               float* __restrict__ outp) {
  __shared__ float s1[PVH * LW], s2[PVH * LW];
  int plane = blockIdx.z;
  int ch = plane & 63;
  int x0 = blockIdx.x * TW, y0 = blockIdx.y * TH;
  const float* hp = hidden + (long)plane * N_PIX;
  const float* vp = vpre + (long)plane * N_PIX;
  const float* op_ = om + (long)plane * N_PIX;
  float lam = sm[OFF_LAM];
  int t = threadIdx.x;
  // phase A: stage hidden + v_pre (rows gy = y0-3..y0+18, cols x0-4..x0+131)
  for (int j = t; j < PVH * 34; j += 256) {
    int row = j / 34, c4 = j - row * 34;
    int gy = y0 - 3 + row, gx = x0 - 4 + c4 * 4;
    *reinterpret_cast<float4*>(s1 + row * LW + c4 * 4) = load_g4(hp, gy, gx);
    *reinterpret_cast<float4*>(s2 + row * LW + c4 * 4) = load_g4(vp, gy, gx);
  }
  __syncthreads();

  int ct = t & 127, rg = t >> 7;
  // phase V: q = dw3(hidden), v = dw3(v_pre) at rows gy=y0-2..y0+17, cols gx=x0-2..x0+129
  int rsV = rg * 10;            // s-rows rsV..rsV+11
  int ciV0 = 2 + ct;            // 2..129
  int ciV1 = 130 + ct;          // ct<4 -> 130..133
  float p1m[10], p1e[10], p2m[10], p2e[10];
  {
    const float* wp = wq + ch * 9;
    float w00 = wp[0], w01 = wp[1], w02 = wp[2], w10 = wp[3], w11 = wp[4],
          w12 = wp[5], w20 = wp[6], w21 = wp[7], w22 = wp[8];
    dw3_col10(s1, ciV0, rsV, w00, w01, w02, w10, w11, w12, w20, w21, w22, p1m);
    if (ct < 4)
      dw3_col10(s1, ciV1, rsV, w00, w01, w02, w10, w11, w12, w20, w21, w22, p1e);
  }
  {
    const float* wp = wv + ch * 9;
    float w00 = wp[0], w01 = wp[1], w02 = wp[2], w10 = wp[3], w11 = wp[4],
          w12 = wp[5], w20 = wp[6], w21 = wp[7], w22 = wp[8];
    dw3_col10(s2, ciV0, rsV, w00, w01, w02, w10, w11, w12, w20, w21, w22, p2m);
    if (ct < 4)
      dw3_col10(s2, ciV1, rsV, w00, w01, w02, w10, w11, w12, w20, w21, w22, p2e);
  }
  {
    int gx0 = x0 - 4 + ciV0, gx1 = x0 - 4 + ciV1;
    bool vx0 = (unsigned)gx0 < 384u, vx1 = (unsigned)gx1 < 384u;
    #pragma unroll
    for (int ii = 0; ii < 10; ii++) {
      int gy = y0 - 2 + rsV + ii;
      bool oky = (unsigned)gy < 384u;
      if (oky && vx0) {
        float o = op_[gy * 384 + gx0];
        p1m[ii] = p1m[ii] * o;
        float vv = p2m[ii];
        p2m[ii] = vv - lam * vv * o;
      } else { p1m[ii] = 0.f; p2m[ii] = 0.f; }
      if (ct < 4) {
        if (oky && vx1) {
          float o = op_[gy * 384 + gx1];
          p1e[ii] = p1e[ii] * o;
          float vv = p2e[ii];
          p2e[ii] = vv - lam * vv * o;
        } else { p1e[ii] = 0.f; p2e[ii] = 0.f; }
      }
    }
  }
  __syncthreads();   // all raw hidden/v_pre reads done
  // write p1 -> s1 rows 1..20, p2 -> s2 rows 1..20
  #pragma unroll
  for (int ii = 0; ii < 10; ii++) {
    s1[(rsV + 1 + ii) * LW + ciV0] = p1m[ii];
    s2[(rsV + 1 + ii) * LW + ciV0] = p2m[ii];
  }
  if (ct < 4) {
    #pragma unroll
    for (int ii = 0; ii < 10; ii++) {
      s1[(rsV + 1 + ii) * LW + ciV1] = p1e[ii];
      s2[(rsV + 1 + ii) * LW + ciV1] = p2e[ii];
    }
  }
  __syncthreads();   // p visible
  // phase B: u1 = prelu(dw3(p1,w1a),a1), u2 = prelu(dw3(p2,w2a),a2)
  float* s1p = s1 + LW;   // p1 rows viewed 0..19
  float* s2p = s2 + LW;
  int rs0 = rg * 9;
  int ci0 = 3 + ct, ci1 = 131 + ct;
  bool xok0 = (unsigned)(x0 - 4 + ci0) < 384u;
  bool xok1 = (unsigned)(x0 - 4 + ci1) < 384u;
  float u1m[9], u1e[9], u2m[9], u2e[9];
  {
    const float* wp1 = w1a + ch * 9;
    float w00 = wp1[0], w01 = wp1[1], w02 = wp1[2], w10 = wp1[3], w11 = wp1[4],
          w12 = wp1[5], w20 = wp1[6], w21 = wp1[7], w22 = wp1[8];
    float alpha = a1p[0];
    stencil_col9(s1p, ci0, rs0, w00, w01, w02, w10, w11, w12, w20, w21, w22, alpha, xok0, y0, u1m);
    if (ct < 2)
      stencil_col9(s1p, ci1, rs0, w00, w01, w02, w10, w11, w12, w20, w21, w22, alpha, xok1, y0, u1e);
  }
  {
    const float* wp2 = w2a + ch * 9;
    float w00 = wp2[0], w01 = wp2[1], w02 = wp2[2], w10 = wp2[3], w11 = wp2[4],
          w12 = wp2[5], w20 = wp2[6], w21 = wp2[7], w22 = wp2[8];
    float alpha = a2p[0];
    stencil_col9(s2p, ci0, rs0, w00, w01, w02, w10, w11, w12, w20, w21, w22, alpha, xok0, y0, u2m);
    if (ct < 2)
      stencil_col9(s2p, ci1, rs0, w00, w01, w02, w10, w11, w12, w20, w21, w22, alpha, xok1, y0, u2e);
  }
  __syncthreads();   // all p reads done
  // write u1 -> s1p rows 1..18 (s1 rows 2..19), u2 -> s2p rows 1..18
  #pragma unroll
  for (int ii = 0; ii < 9; ii++) {
    s1p[(rs0 + ii + 1) * LW + ci0] = u1m[ii];
    s2p[(rs0 + ii + 1) * LW + ci0] = u2m[ii];
  }
  if (ct < 2) {
    #pragma unroll
    for (int ii = 0; ii < 9; ii++) {
      s1p[(rs0 + ii + 1) * LW + ci1] = u1e[ii];
      s2p[(rs0 + ii + 1) * LW + ci1] = u2e[ii];
    }
  }
  __syncthreads();   // u visible
  // phase C: out = dw3(u1,w1b) + dw3(u2,w2b)
  {
    const float* wp1 = w1b + ch * 9;
    const float* wp2 = w2b + ch * 9;
    float p00 = wp1[0], p01 = wp1[1], p02 = wp1[2], p10 = wp1[3], p11 = wp1[4], p12 = wp1[5], p20 = wp1[6], p21 = wp1[7], p22 = wp1[8];
    float q00 = wp2[0], q01 = wp2[1], q02 = wp2[2], q10 = wp2[3], q11 = wp2[4], q12 = wp2[5], q20 = wp2[6], q21 = wp2[7], q22 = wp2[8];
    int col = t & 127, rg2 = t >> 7;
    int lc = col + 4;
    int rb = rg2 * 8 + 1;
    float xa0 = s1p[rb * LW + lc - 1],       xa1 = s1p[rb * LW + lc],       xa2 = s1p[rb * LW + lc + 1];
    float xb0 = s1p[(rb + 1) * LW + lc - 1], xb1 = s1p[(rb + 1) * LW + lc], xb2 = s1p[(rb + 1) * LW + lc + 1];
    float ya0 = s2p[rb * LW + lc - 1],       ya1 = s2p[rb * LW + lc],       ya2 = s2p[rb * LW + lc + 1];
    float yb0 = s2p[(rb + 1) * LW + lc - 1], yb1 = s2p[(rb + 1) * LW + lc], yb2 = s2p[(rb + 1) * LW + lc + 1];
    float* wo = outp + (long)plane * N_PIX + (long)(y0 + rg2 * 8) * 384 + x0 + col;
    #pragma unroll
    for (int i = 0; i < 8; i++) {
      int lr = rb + i + 2;
      float xc0 = s1p[lr * LW + lc - 1], xc1 = s1p[lr * LW + lc], xc2 = s1p[lr * LW + lc + 1];
      float yc0 = s2p[lr * LW + lc - 1], yc1 = s2p[lr * LW + lc], yc2 = s2p[lr * LW + lc + 1];
      float s = p00 * xa0;
      s = fmaf(p01, xa1, s); s = fmaf(p02, xa2, s);
      s = fmaf(p10, xb0, s); s = fmaf(p11, xb1, s); s = fmaf(p12, xb2, s);
      s = fmaf(p20, xc0, s); s = fmaf(p21, xc1, s); s = fmaf(p22, xc2, s);
      s = fmaf(q00, ya0, s); s = fmaf(q01, ya1, s); s = fmaf(q02, ya2, s);
      s = fmaf(q10, yb0, s); s = fmaf(q11, yb1, s); s = fmaf(q12, yb2, s);
      s = fmaf(q20, yc0, s); s = fmaf(q21, yc1, s); s = fmaf(q22, yc2, s);
      wo[i * 384] = s;
      xa0 = xb0; xa1 = xb1; xa2 = xb2; xb0 = xc0; xb1 = xc1; xb2 = xc2;
      ya0 = yb0; ya1 = yb1; ya2 = yb2; yb0 = yc0; yb1 = yc1; yb2 = yc2;
    }
  }
}

// ---------------------------------------------------------------- Gram + norms + fused out1 = qf*kf (in-place over kf)
#define GS_P 132
__global__ __launch_bounds__(256) void gram_k(const float* __restrict__ qf, float* __restrict__ kf,
                                              float* __restrict__ sm) {
  __shared__ float qs[16 * GS_P], ks[16 * GS_P];
  int t = threadIdx.x;
  int bh = blockIdx.y;
  int bb = bh >> 2, h = bh & 3;
  const float* qbase = qf + ((long)bb * 64 + h * 16) * L_LEN;
  float* kbase = kf + ((long)bb * 64 + h * 16) * L_LEN;
  int c = t >> 4, d = t & 15;
  long l0 = (long)blockIdx.x * 2048;
  float g = 0.f, nq = 0.f, nk = 0.f;
  for (int chunk = 0; chunk < 16; chunk++) {
    long lc = l0 + chunk * 128;
    __syncthreads();
    for (int j = t; j < 512; j += 256) {
      int row = j >> 5, c4 = j & 31;
      float4 qv = *reinterpret_cast<const float4*>(qbase + (long)row * L_LEN + lc + c4 * 4);
      float4 kv = *reinterpret_cast<const float4*>(kbase + (long)row * L_LEN + lc + c4 * 4);
      *reinterpret_cast<float4*>(qs + row * GS_P + c4 * 4) = qv;
      *reinterpret_cast<float4*>(ks + row * GS_P + c4 * 4) = kv;
      // fused product write-back (each element owned by exactly one block)
      *reinterpret_cast<float4*>(kbase + (long)row * L_LEN + lc + c4 * 4) =
          make_float4(qv.x * kv.x, qv.y * kv.y, qv.z * kv.z, qv.w * kv.w);
    }
    __syncthreads();
    #pragma unroll
    for (int i = 0; i < 128; i += 4) {
      float4 a = *reinterpret_cast<const float4*>(qs + c * GS_P + i);
      float4 b = *reinterpret_cast<const float4*>(ks + d * GS_P + i);
      g  = fmaf(a.x, b.x, g);  g  = fmaf(a.y, b.y, g);  g  = fmaf(a.z, b.z, g);  g  = fmaf(a.w, b.w, g);
      nq = fmaf(a.x, a.x, nq); nq = fmaf(a.y, a.y, nq); nq = fmaf(a.z, a.z, nq); nq = fmaf(a.w, a.w, nq);
      nk = fmaf(b.x, b.x, nk); nk = fmaf(b.y, b.y, nk); nk = fmaf(b.z, b.z, nk); nk = fmaf(b.w, b.w, nk);
    }
  }
  atomicAdd(&sm[OFF_GRAM + bh * 256 + c * 16 + d], g);
  if (d == 0) atomicAdd(&sm[OFF_QQ + bh * 16 + c], nq);
  if (c == 0) atomicAdd(&sm[OFF_KK + bh * 16 + d], nk);
}

// ---------------------------------------------------------------- normalize + temperature + softmax over d
__global__ __launch_bounds__(256) void attn_k(const float* __restrict__ temp, float* __restrict__ sm) {
  int bh = blockIdx.x;
  int h = bh & 3;
  int t = threadIdx.x;
  int c = t >> 4, d = t & 15;
  float qn = fmaxf(sqrtf(sm[OFF_QQ + bh * 16 + c]), 1e-12f);
  float kn = fmaxf(sqrtf(sm[OFF_KK + bh * 16 + d]), 1e-12f);
  float v = sm[OFF_GRAM + bh * 256 + t] / (qn * kn) * temp[h];
  float mx = v;
  #pragma unroll
  for (int o = 8; o; o >>= 1) mx = fmaxf(mx, __shfl_xor(mx, o, 16));
  float e = expf(v - mx);
  float s = e;
  #pragma unroll
  for (int o = 8; o; o >>= 1) s += __shfl_xor(s, o, 16);
  sm[OFF_ATTN + bh * 256 + t] = e / s;
}

// ---------------------------------------------------------------- fused combine + idct (reads out1 only)
#define CB_P 273
__global__ __launch_bounds__(256) void comb_idct_k(const float* __restrict__ of,
                                                   const float* __restrict__ sm, float* __restrict__ out) {
  __shared__ float A[256];
  __shared__ float Ci[64];
  __shared__ float sb[16 * CB_P];
  int bh = blockIdx.y;
  int t = threadIdx.x;
  A[t] = sm[OFF_ATTN + bh * 256 + t];
  if (t < 64) Ci[t] = sm[OFF_CI + t];
  __syncthreads();
  int bb = bh >> 2, h = bh & 3;
  long l = (long)blockIdx.x * 256 + t;
  const float* kp = of + ((long)bb * 64 + h * 16) * L_LEN + l;
  float p[16];
  #pragma unroll
  for (int d = 0; d < 16; d++) p[d] = kp[(long)d * L_LEN];
  int pl_w = t >> 6, i_w = t & 63;
  #pragma unroll
  for (int c = 0; c < 16; c++) {
    float s = 0.f;
    #pragma unroll
    for (int d = 0; d < 16; d++) s = fmaf(A[c * 16 + d], p[d], s);
    sb[c * CB_P + pl_w * 68 + i_w] = s;
  }
  __syncthreads();
  int j = t & 3, c = (t >> 2) & 15, pl = t >> 6;
  const float* fb = sb + c * CB_P + pl * 68;
  float F[8][8];
  #pragma unroll
  for (int a = 0; a < 8; a++)
    #pragma unroll
    for (int b8 = 0; b8 < 8; b8++) F[a][b8] = fb[a * 8 + b8];
  int patch = blockIdx.x * 4 + pl;
  int hy = patch / 48, wx = patch - hy * 48;
  float* op = out + ((long)bb * 64 + h * 16 + c) * N_PIX + (long)(hy * 8) * 384 + wx * 8;
  #pragma unroll
  for (int mm = 0; mm < 2; mm++) {
    int m = 2 * j + mm;
    float T[8];
    #pragma unroll
    for (int b8 = 0; b8 < 8; b8++) {
      float s = 0.f;
      #pragma unroll
      for (int a = 0; a < 8; a++) s = fmaf(Ci[m * 8 + a], F[a][b8], s);
      T[b8] = s;
    }
    float o[8];
    #pragma unroll
    for (int n = 0; n < 8; n++) {
      float s = 0.f;
      #pragma unroll
      for (int b8 = 0; b8 < 8; b8++) s = fmaf(Ci[n * 8 + b8], T[b8], s);
      o[n] = s;
    }
    *reinterpret_cast<float4*>(op + m * 384)     = make_float4(o[0], o[1], o[2], o[3]);
    *reinterpret_cast<float4*>(op + m * 384 + 4) = make_float4(o[4], o[5], o[6], o[7]);
  }
}

// ---------------------------------------------------------------- launch
extern "C" void kernel_launch(void* const* d_in, const int* in_sizes, int n_in,
                              void* d_out, int out_size, void* d_ws, size_t ws_size,
                              hipStream_t stream) {
  const float* x            = (const float*)d_in[0];
  const float* nir          = (const float*)d_in[1];
  const float* w_hidden     = (const float*)d_in[2];
  const float* w_hidden_nir = (const float*)d_in[3];
  const float* w_dw         = (const float*)d_in[4];
  const float* w_dw_nir     = (const float*)d_in[5];
  const float* temperature  = (const float*)d_in[6];
  const float* w_proj_mid   = (const float*)d_in[7];
  const float* w_proj_out   = (const float*)d_in[8];
  const float* w_p1a        = (const float*)d_in[9];
  const float* a_p1         = (const float*)d_in[10];
  const float* w_p1b        = (const float*)d_in[11];
  const float* w_p2a        = (const float*)d_in[12];
  const float* a_p2         = (const float*)d_in[13];
  const float* w_p2b        = (const float*)d_in[14];
  const float* lq1          = (const float*)d_in[15];
  const float* lk1          = (const float*)d_in[16];
  const float* lq2          = (const float*)d_in[17];
  const float* lk2          = (const float*)d_in[18];

  float* OUT = (float*)d_out;
  float* W0 = (float*)d_ws;
  float* W1 = W0 + TENS_SZ;
  float* W2 = W1 + TENS_SZ;
  float* SM = W2 + TENS_SZ;

  size_t needed = (size_t)3 * TENS_SZ * sizeof(float) + 32768;
  if (ws_size < needed) {
    diag_k<<<1, 1, 0, stream>>>(OUT, 1000.0f + (float)(ws_size >> 20));
    return;
  }

  dim3 blk256(256);
  dim3 gridST(3, 24, NB * 64);     // stencil tiles: 128x16 over 384x384, 128 planes

  init_k<<<1, 64, 0, stream>>>(lq1, lk1, lq2, lk2, SM);
  // k_pre -> W2, v_pre -> W1 (nir read once; v_pre lives until pool3)
  conv1x1_nir2_k<<<1152, blk256, 0, stream>>>(nir, w_hidden_nir, W2, W1);
  // k_fft = dct(dw3(k_pre)) -> OUT
  dw3dct_k<<<gridST, blk256, 0, stream>>>(W2, w_dw_nir, SM, OUT);
  // hidden = conv1x1(x, w_hidden) -> W0 (lives until pool3)
  conv1x1_k<<<1152, blk256, 0, stream>>>(x, w_hidden, W0);
  // q_fft = dct(dw3(hidden)) -> W2
  dw3dct_k<<<gridST, blk256, 0, stream>>>(W0, w_dw, SM, W2);
  // gram + norms + fused out1 = q_fft*k_fft (in-place over OUT); q_fft dead after
  gram_k<<<dim3(72, 8), blk256, 0, stream>>>(W2, OUT, SM);
  attn_k<<<8, blk256, 0, stream>>>(temperature, SM);
  // o spatial = idct(attn @ out1) -> W2
  comb_idct_k<<<dim3(576, 8), blk256, 0, stream>>>(OUT, SM, W2);
  // om = conv1x1(o, w_proj_mid) -> OUT (out1 dead)
  conv1x1_k<<<1152, blk256, 0, stream>>>(W2, w_proj_mid, OUT);
  // pool3: hidden=W0, v_pre=W1, om=OUT -> outp = W2 (o dead)
  pool3_k<<<gridST, blk256, 0, stream>>>(W0, W1, OUT, w_dw, w_dw_nir + 64 * 9,
                                         w_p1a, a_p1, w_p1b, w_p2a, a_p2, w_p2b, SM, W2);
  // final = conv1x1(outp, w_proj_out) -> OUT
  conv1x1_k<<<1152, blk256, 0, stream>>>(W2, w_proj_out, OUT);
}